// Round 22
// baseline (120.316 us; speedup 1.0000x reference)
//
#include <hip/hip_runtime.h>
#include <hip/hip_bf16.h>

#define DIM   128
#define NH    8
#define INNER 512
#define HD    64
#define BSZ   4
#define NSEQ  1024
#define PEC   32
#define BH    32   // BSZ*NH

typedef __attribute__((ext_vector_type(4))) float f32x4;
typedef __attribute__((ext_vector_type(2))) float f32x2;
typedef __attribute__((ext_vector_type(8))) short s16x8;
typedef __attribute__((ext_vector_type(4))) unsigned short u16x4;
typedef __attribute__((ext_vector_type(2))) unsigned int u32x2;
typedef __attribute__((ext_vector_type(4))) unsigned int u32x4;

__device__ __forceinline__ unsigned short f2bf(float f) {
    unsigned u = __float_as_uint(f);
    u += 0x7fffu + ((u >> 16) & 1u);
    return (unsigned short)(u >> 16);
}

__device__ __forceinline__ float bf2f(short s) {
    return __uint_as_float(((unsigned)(unsigned short)s) << 16);
}

__device__ __forceinline__ s16x8 load8bf(const float* p) {
    f32x4 a = *(const f32x4*)p;
    f32x4 b = *(const f32x4*)(p + 4);
    s16x8 r;
    r[0] = (short)f2bf(a[0]); r[1] = (short)f2bf(a[1]);
    r[2] = (short)f2bf(a[2]); r[3] = (short)f2bf(a[3]);
    r[4] = (short)f2bf(b[0]); r[5] = (short)f2bf(b[1]);
    r[6] = (short)f2bf(b[2]); r[7] = (short)f2bf(b[3]);
    return r;
}

__device__ __forceinline__ f32x4 mfma16(s16x8 a, s16x8 b, f32x4 c) {
    return __builtin_amdgcn_mfma_f32_16x16x32_bf16(a, b, c, 0, 0, 0);
}

// ---------------------------------------------------------------------------
// K1 v3: q/k/v projections, LDS-staged x + 4 m-subtiles per wave.  [R15]
// grid (24, 64), block 256.
// ---------------------------------------------------------------------------
__global__ __launch_bounds__(256) void k_qkv(
    const float* __restrict__ x,
    const float* __restrict__ Wq, const float* __restrict__ Wk,
    const float* __restrict__ Wv, const float* __restrict__ bv,
    unsigned short* __restrict__ qws, unsigned short* __restrict__ kws,
    unsigned short* __restrict__ vtws)
{
    __shared__ unsigned short xs[64][136];   // 17.4 KB, +8 pad
    int lane = threadIdx.x & 63, wave = threadIdx.x >> 6;
    int lr = lane & 15, lg = lane >> 4;
    int ct   = blockIdx.x * 4 + wave;        // 0..95 column tile over 1536 cols
    int col0 = ct * 16;
    int m0   = blockIdx.y * 64;

    int tid = threadIdx.x;
    #pragma unroll
    for (int it = 0; it < 4; ++it) {
        int flat = it * 256 + tid;           // 0..1023
        int r = flat >> 4, c8 = (flat & 15) * 8;
        *(s16x8*)&xs[r][c8] = load8bf(x + (m0 + r) * DIM + c8);
    }
    __syncthreads();

    const float* W; int cbase; int which = col0 >> 9;
    if (which == 0)      { W = Wq; cbase = col0; }
    else if (which == 1) { W = Wk; cbase = col0 - 512; }
    else                 { W = Wv; cbase = col0 - 1024; }

    const float* wrow = W + (cbase + lr) * DIM;
    s16x8 bfr[4];
    #pragma unroll
    for (int kt = 0; kt < 4; ++kt) bfr[kt] = load8bf(wrow + kt * 32 + lg * 8);

    if (which == 2) {
        int colW = cbase + lr;
        int h = colW >> 6, d = colW & 63;
        float bias = bv[colW];
        #pragma unroll
        for (int ms = 0; ms < 4; ++ms) {
            f32x4 acc = {0.f, 0.f, 0.f, 0.f};
            #pragma unroll
            for (int kt = 0; kt < 4; ++kt) {
                s16x8 a = *(const s16x8*)&xs[ms * 16 + lr][kt * 32 + lg * 8];
                acc = mfma16(a, bfr[kt], acc);
            }
            int mB = m0 + ms * 16 + lg * 4;
            int b  = mB >> 10;
            int bh = b * NH + h;
            u16x4 pk;
            #pragma unroll
            for (int v = 0; v < 4; ++v) pk[v] = f2bf(acc[v] + bias);
            int n0 = mB & 1023;
            *(u16x4*)(vtws + (bh * HD + d) * NSEQ + n0) = pk;
        }
    } else {
        int h = cbase >> 6;
        int dbase = (cbase & 63) + lg * 4;
        unsigned short* dst = (which == 0) ? qws : kws;
        float scale = (which == 0) ? 0.125f : 1.0f;
        #pragma unroll
        for (int ms = 0; ms < 4; ++ms) {
            f32x4 acc = {0.f, 0.f, 0.f, 0.f};
            #pragma unroll
            for (int kt = 0; kt < 4; ++kt) {
                s16x8 a = *(const s16x8*)&xs[ms * 16 + lr][kt * 32 + lg * 8];
                acc = mfma16(bfr[kt], a, acc);   // A=W rows, B=x rows
            }
            int m = m0 + ms * 16 + lr;
            int b = m >> 10, n = m & 1023;
            int bh = b * NH + h;
            u16x4 pk;
            #pragma unroll
            for (int v = 0; v < 4; ++v) pk[v] = f2bf(acc[v] * scale);
            *(u16x4*)(dst + ((size_t)bh * NSEQ + n) * HD + dbase) = pk;
        }
    }
}

// ---------------------------------------------------------------------------
// K2 v9: k_fattn — flash attention per (bh, 32-row i-tile).  [R17, unchanged]
//   P copy-out as fp8 e4m3 x256; PV keeps bf16 P in LDS.
// grid 1024 (XCD-pinned bh), block 256.
// ---------------------------------------------------------------------------
__global__ __launch_bounds__(256, 2) void k_fattn(
    const unsigned short* __restrict__ qws, const unsigned short* __restrict__ kws,
    const unsigned short* __restrict__ vtws,
    unsigned char* __restrict__ attn8, float* __restrict__ outv)
{
    __shared__ unsigned short Pl[32 * 1024];   // 64 KB P [i-local][j] swizzled
    __shared__ float mlb[4][2][16][2];         // [wave][i-half][lr][{max,sum}]
    int lane = threadIdx.x & 63, wave = threadIdx.x >> 6;
    int lr = lane & 15, lg = lane >> 4;
    int L = blockIdx.x;
    int bh = (L & 7) * 4 + ((L >> 3) & 3);   // XCD-pinned: K/V L2-resident
    int i0 = (L >> 5) * 32;

    auto paddr = [&](int r, int jb) -> char* {
        unsigned mask = (unsigned)(((r & 7) << 4) | ((r & 3) << 7));
        return (char*)Pl + (unsigned)(r * 2048) + ((unsigned)jb ^ mask);
    };

    // q fragments (B operand: B-row = i)
    s16x8 qf[2][2];
    #pragma unroll
    for (int m = 0; m < 2; ++m) {
        const unsigned short* qrow = qws + (bh * NSEQ + i0 + m * 16 + lr) * HD;
        qf[m][0] = *(const s16x8*)(qrow + lg * 8);
        qf[m][1] = *(const s16x8*)(qrow + 32 + lg * 8);
    }

    // ---- phase A: S for this wave's j-quarter, in registers ----
    f32x4 s[16][2];
    #pragma unroll
    for (int jc = 0; jc < 16; ++jc) {
        const unsigned short* krow =
            kws + (bh * NSEQ + wave * 256 + jc * 16 + lr) * HD + lg * 8;
        s16x8 kf0 = *(const s16x8*)(krow);
        s16x8 kf1 = *(const s16x8*)(krow + 32);
        #pragma unroll
        for (int m = 0; m < 2; ++m) {
            f32x4 acc = {0.f, 0.f, 0.f, 0.f};
            acc = mfma16(kf0, qf[m][0], acc);
            s[jc][m] = mfma16(kf1, qf[m][1], acc);
        }
    }

    // wave-local stats per i
    float mx[2], sm[2];
    #pragma unroll
    for (int m = 0; m < 2; ++m) {
        float v = -3.0e38f;
        #pragma unroll
        for (int jc = 0; jc < 16; ++jc) {
            f32x4 t = s[jc][m];
            v = fmaxf(v, fmaxf(fmaxf(t[0], t[1]), fmaxf(t[2], t[3])));
        }
        v = fmaxf(v, __shfl_xor(v, 16));
        v = fmaxf(v, __shfl_xor(v, 32));
        mx[m] = v;
    }
    #pragma unroll
    for (int m = 0; m < 2; ++m) {
        float sum = 0.f;
        #pragma unroll
        for (int jc = 0; jc < 16; ++jc) {
            f32x4 t = s[jc][m];
            #pragma unroll
            for (int u = 0; u < 4; ++u) { t[u] = __expf(t[u] - mx[m]); sum += t[u]; }
            s[jc][m] = t;
        }
        sum += __shfl_xor(sum, 16);
        sum += __shfl_xor(sum, 32);
        sm[m] = sum;
    }
    if (lg == 0) {
        #pragma unroll
        for (int m = 0; m < 2; ++m) {
            mlb[wave][m][lr][0] = mx[m];
            mlb[wave][m][lr][1] = sm[m];
        }
    }
    __syncthreads();

    // global M, L across the 4 waves; per-wave normalization factor
    float f[2];
    #pragma unroll
    for (int m = 0; m < 2; ++m) {
        float M = -3.0e38f;
        #pragma unroll
        for (int w = 0; w < 4; ++w) M = fmaxf(M, mlb[w][m][lr][0]);
        float Ls = 0.f;
        #pragma unroll
        for (int w = 0; w < 4; ++w)
            Ls += mlb[w][m][lr][1] * __expf(mlb[w][m][lr][0] - M);
        f[m] = __expf(mx[m] - M) / Ls;
    }

    // scale + pack bf16 -> LDS P (wave-private j columns, disjoint)
    #pragma unroll
    for (int jc = 0; jc < 16; ++jc) {
        #pragma unroll
        for (int m = 0; m < 2; ++m) {
            f32x4 t = s[jc][m];
            unsigned lo = (unsigned)f2bf(t[0] * f[m]) | ((unsigned)f2bf(t[1] * f[m]) << 16);
            unsigned hi = (unsigned)f2bf(t[2] * f[m]) | ((unsigned)f2bf(t[3] * f[m]) << 16);
            u32x2 pk = {lo, hi};
            int r  = m * 16 + lr;
            int jb = (wave * 512) + (jc * 32) + (lg * 8);
            *(u32x2*)paddr(r, jb) = pk;
        }
    }
    __syncthreads();

    // ---- P copy-out FIRST as fp8 (x256): 16 j per lane, one 16B store ----
    #pragma unroll
    for (int r8 = 0; r8 < 8; ++r8) {
        int r = wave * 8 + r8;
        s16x8 a = *(s16x8*)paddr(r, lane * 32);
        s16x8 b = *(s16x8*)paddr(r, lane * 32 + 16);
        u32x4 w;
        #pragma unroll
        for (int q = 0; q < 2; ++q) {
            s16x8 v = q ? b : a;
            #pragma unroll
            for (int dw = 0; dw < 2; ++dw) {
                unsigned pk = __builtin_amdgcn_cvt_pk_fp8_f32(
                    bf2f(v[dw * 4 + 0]) * 256.f, bf2f(v[dw * 4 + 1]) * 256.f, 0u, false);
                pk = __builtin_amdgcn_cvt_pk_fp8_f32(
                    bf2f(v[dw * 4 + 2]) * 256.f, bf2f(v[dw * 4 + 3]) * 256.f, pk, true);
                w[q * 2 + dw] = pk;
            }
        }
        *(u32x4*)(attn8 + ((size_t)(i0 + r) * BH + bh) * NSEQ + lane * 16) = w;
    }

    // ---- phase B: PV; wave owns d-16 (all j from LDS, bf16) ----
    int d0 = wave * 16;
    const unsigned short* vrow = vtws + (bh * HD + d0 + lr) * NSEQ + lg * 8;
    f32x4 o0 = {0.f, 0.f, 0.f, 0.f};
    f32x4 o1 = {0.f, 0.f, 0.f, 0.f};
    #pragma unroll
    for (int kt = 0; kt < 32; ++kt) {
        s16x8 bf = *(const s16x8*)(vrow + kt * 32);
        s16x8 a0 = *(s16x8*)paddr(lr,      kt * 64 + lg * 16);
        s16x8 a1 = *(s16x8*)paddr(16 + lr, kt * 64 + lg * 16);
        o0 = mfma16(a0, bf, o0);
        o1 = mfma16(a1, bf, o1);
    }
    float* orow = outv + (bh * NSEQ + i0) * HD;
    #pragma unroll
    for (int v = 0; v < 4; ++v) {
        orow[(lg * 4 + v) * HD + d0 + lr]      = o0[v];
        orow[(16 + lg * 4 + v) * HD + d0 + lr] = o1[v];
    }
}

// ---------------------------------------------------------------------------
// K3 v12: k_pe4 — split-K pe-GEMM.  Block (i, jq) handles K=256 j's:
//   per-wave chain is 2 issue/commit/consume steps (was 8) -> 4x less exposed
//   L3 latency per block; 4096 blocks give 4 sequential passes/CU that
//   pipeline each other.  Partials (f32) -> pesp[jq][bh][i][c]; reduced in
//   k_out.  pe still read exactly once globally.
// grid 4096 (= i*4 + jq), block 256 (4 waves).  LDS 36 KB -> 4 blocks/CU.
// ---------------------------------------------------------------------------
__global__ __launch_bounds__(256) void k_pe4(
    const unsigned char* __restrict__ attn8, const float* __restrict__ pe,
    float* __restrict__ pesp)
{
    __shared__ unsigned short pt[4][2][PEC][40];   // per-wave dbuf pe^T, 20 KB
    __shared__ float part[4][BH][PEC];             // partials, 16 KB
    int L = blockIdx.x;
    int i = L >> 2, jq = L & 3;
    int tid = threadIdx.x;
    int lane = tid & 63, wave = tid >> 6;
    int lr = lane & 15, lg = lane >> 4;
    int jp = lane & 15, cg = lane >> 4;            // staging roles
    const float* pei = pe + (size_t)i * NSEQ * PEC;
    int jbase = jq * 256 + wave * 64;              // this wave's 64 j

    // 4 fragment loads (fp8 -> bf16), short chain
    s16x8 af[2][2];
    #pragma unroll
    for (int t = 0; t < 2; ++t) {
        #pragma unroll
        for (int mh = 0; mh < 2; ++mh) {
            const unsigned char* ap =
                attn8 + ((size_t)i * BH + mh * 16 + lr) * NSEQ + jbase + t * 32 + lg * 8;
            u32x2 dd = *(const u32x2*)ap;
            f32x2 p0 = __builtin_amdgcn_cvt_pk_f32_fp8(dd[0], false);
            f32x2 p1 = __builtin_amdgcn_cvt_pk_f32_fp8(dd[0], true);
            f32x2 p2 = __builtin_amdgcn_cvt_pk_f32_fp8(dd[1], false);
            f32x2 p3 = __builtin_amdgcn_cvt_pk_f32_fp8(dd[1], true);
            s16x8 fv;
            fv[0] = (short)f2bf(p0[0]); fv[1] = (short)f2bf(p0[1]);
            fv[2] = (short)f2bf(p1[0]); fv[3] = (short)f2bf(p1[1]);
            fv[4] = (short)f2bf(p2[0]); fv[5] = (short)f2bf(p2[1]);
            fv[6] = (short)f2bf(p3[0]); fv[7] = (short)f2bf(p3[1]);
            af[t][mh] = fv;
        }
    }

    f32x4 r0, r1, r2, r3;        // pe stage registers
    auto issue = [&](int t) {
        const float* s0 = pei + (size_t)(jbase + t * 32 + jp * 2) * PEC + cg * 8;
        r0 = *(const f32x4*)(s0);
        r1 = *(const f32x4*)(s0 + 4);
        r2 = *(const f32x4*)(s0 + PEC);
        r3 = *(const f32x4*)(s0 + PEC + 4);
    };
    auto commit = [&](int buf) {
        #pragma unroll
        for (int cc = 0; cc < 4; ++cc) {
            unsigned lo = f2bf(r0[cc]), hi = f2bf(r2[cc]);
            *(unsigned*)&pt[wave][buf][cg * 8 + cc][jp * 2] = lo | (hi << 16);
        }
        #pragma unroll
        for (int cc = 0; cc < 4; ++cc) {
            unsigned lo = f2bf(r1[cc]), hi = f2bf(r3[cc]);
            *(unsigned*)&pt[wave][buf][cg * 8 + 4 + cc][jp * 2] = lo | (hi << 16);
        }
    };

    f32x4 acc00 = {0.f,0.f,0.f,0.f}, acc01 = {0.f,0.f,0.f,0.f};
    f32x4 acc10 = {0.f,0.f,0.f,0.f}, acc11 = {0.f,0.f,0.f,0.f};

    issue(0); commit(0);
    issue(1);
    #pragma unroll
    for (int t = 0; t < 2; ++t) {
        int cur = t & 1;
        s16x8 bf0 = *(const s16x8*)&pt[wave][cur][lr][lg * 8];
        s16x8 bf1 = *(const s16x8*)&pt[wave][cur][16 + lr][lg * 8];
        acc00 = mfma16(af[t][0], bf0, acc00);
        acc01 = mfma16(af[t][0], bf1, acc01);
        acc10 = mfma16(af[t][1], bf0, acc10);
        acc11 = mfma16(af[t][1], bf1, acc11);
        if (t == 0) commit(1);
    }

    // partial store: C row = bh-in-half = lg*4+v, col = c-in-half = lr
    #pragma unroll
    for (int v = 0; v < 4; ++v) {
        part[wave][lg * 4 + v][lr]           = acc00[v];
        part[wave][lg * 4 + v][16 + lr]      = acc01[v];
        part[wave][16 + lg * 4 + v][lr]      = acc10[v];
        part[wave][16 + lg * 4 + v][16 + lr] = acc11[v];
    }
    __syncthreads();

    int bh = tid >> 3, c0 = (tid & 7) * 4;
    f32x4 s = *(f32x4*)&part[0][bh][c0];
    #pragma unroll
    for (int w = 1; w < 4; ++w) {
        f32x4 q = *(f32x4*)&part[w][bh][c0];
        s[0] += q[0]; s[1] += q[1]; s[2] += q[2]; s[3] += q[3];
    }
    const float inv256 = 1.0f / 256.0f;
    s[0] *= inv256; s[1] *= inv256; s[2] *= inv256; s[3] *= inv256;
    float* dst = pesp + (size_t)jq * BH * NSEQ * PEC
                      + ((size_t)bh * NSEQ + i) * PEC + c0;
    *(f32x4*)dst = s;
}

// ---------------------------------------------------------------------------
// K4 v3 (fused comb+proj, 4-partial reduce).  grid 256, block 512.
// ---------------------------------------------------------------------------
__global__ __launch_bounds__(512) void k_out(
    const float* __restrict__ outv, const float* __restrict__ pesp,
    const float* __restrict__ Wpe, const float* __restrict__ bpe,
    const float* __restrict__ Wproj, float* __restrict__ out)
{
    __shared__ float wpe_s[HD * PEC];          // 8 KB
    __shared__ float bpe_s[HD];
    __shared__ unsigned short tl[16][520];     // 16.6 KB bf16 t tile, padded
    int tid = threadIdx.x;
    for (int idx = tid; idx < HD * PEC; idx += 512) wpe_s[idx] = Wpe[idx];
    if (tid < HD) bpe_s[tid] = bpe[tid];
    __syncthreads();

    int m0 = blockIdx.x * 16;
    const size_t Q = (size_t)BH * NSEQ * PEC;

    // ---- phase 1: build t tile (each thread: 2 h, 8 d) ----
    {
        int r  = tid >> 5;                     // 0..15
        int o  = tid & 31;
        int d0 = (o & 7) * 8;
        int hp = o >> 3;                       // 0..3
        int m  = m0 + r;
        int b  = m >> 10, n = m & 1023;
        #pragma unroll
        for (int hh = 0; hh < 2; ++hh) {
            int h  = hh * 4 + hp;
            int bh = b * NH + h;
            const float* prow = pesp + ((size_t)bh * NSEQ + n) * PEC;
            float pr[PEC];
            #pragma unroll
            for (int c = 0; c < PEC; c += 4) {
                f32x4 t0 = *(const f32x4*)(prow + c);
                f32x4 t1 = *(const f32x4*)(prow + Q + c);
                f32x4 t2 = *(const f32x4*)(prow + 2 * Q + c);
                f32x4 t3 = *(const f32x4*)(prow + 3 * Q + c);
                pr[c]   = t0[0] + t1[0] + t2[0] + t3[0];
                pr[c+1] = t0[1] + t1[1] + t2[1] + t3[1];
                pr[c+2] = t0[2] + t1[2] + t2[2] + t3[2];
                pr[c+3] = t0[3] + t1[3] + t2[3] + t3[3];
            }
            const float* ovp = outv + ((size_t)bh * NSEQ + n) * HD + d0;
            s16x8 pk;
            #pragma unroll
            for (int dd = 0; dd < 8; ++dd) {
                float acc = bpe_s[d0 + dd] + ovp[dd];
                const float* wr = &wpe_s[(d0 + dd) * PEC];
                #pragma unroll
                for (int c = 0; c < PEC; ++c) acc += pr[c] * wr[c];
                pk[dd] = (short)f2bf(acc);
            }
            *(s16x8*)&tl[r][h * HD + d0] = pk;
        }
    }
    __syncthreads();

    // ---- phase 2: out = t @ Wproj^T ; 8 waves x one 16-col tile ----
    int lane = tid & 63, wave = tid >> 6;
    int lr = lane & 15, lg = lane >> 4;
    int n0 = wave * 16;
    const float* brow = Wproj + (n0 + lr) * INNER;
    f32x4 acc = {0.f, 0.f, 0.f, 0.f};
    #pragma unroll
    for (int kt = 0; kt < 16; ++kt) {
        s16x8 afr = *(const s16x8*)&tl[lr][kt * 32 + lg * 8];
        s16x8 bfr = load8bf(brow + kt * 32 + lg * 8);
        acc = mfma16(afr, bfr, acc);
    }
    #pragma unroll
    for (int v = 0; v < 4; ++v)
        out[(m0 + lg * 4 + v) * DIM + n0 + lr] = acc[v];
}

// ---------------------------------------------------------------------------
// Workspace layout (68 MiB used):
//   [ 0,  4) MiB q_ws   bf16 [bh][n][64]
//   [ 4,  8) MiB k_ws   bf16 [bh][n][64]
//   [ 8, 12) MiB vT_ws  bf16 [bh][64][n]
//   [12, 44) MiB attn8  fp8  [i][bh][j]  (P x256, e4m3)
//   [44, 52) MiB outv   f32  [bh][n][64]
//   [52, 68) MiB pesp   f32  [4][bh][i][32]  (split-K partials)
// Ledger: peout's 8-step serial chain was the limiter; split-K (4 blocks/i)
// cuts the per-block chain to 2 steps and lets passes pipeline.
// ---------------------------------------------------------------------------
extern "C" void kernel_launch(void* const* d_in, const int* in_sizes, int n_in,
                              void* d_out, int out_size, void* d_ws, size_t ws_size,
                              hipStream_t stream)
{
    const float* x     = (const float*)d_in[0];
    const float* pe    = (const float*)d_in[1];
    const float* Wq    = (const float*)d_in[2];
    const float* Wk    = (const float*)d_in[3];
    const float* Wv    = (const float*)d_in[4];
    const float* bv    = (const float*)d_in[5];
    const float* Wproj = (const float*)d_in[6];
    const float* Wpe   = (const float*)d_in[7];
    const float* bpe   = (const float*)d_in[8];
    float* out = (float*)d_out;

    char* ws = (char*)d_ws;
    unsigned short* qws  = (unsigned short*)(ws);
    unsigned short* kws  = (unsigned short*)(ws + ( 4u << 20));
    unsigned short* vtws = (unsigned short*)(ws + ( 8u << 20));
    unsigned char*  attn = (unsigned char*) (ws + (12u << 20));
    float*          outv = (float*)         (ws + (44u << 20));
    float*          pesp = (float*)         (ws + (52u << 20));

    k_qkv  <<<dim3(24, 64), 256, 0, stream>>>(x, Wq, Wk, Wv, bv, qws, kws, vtws);
    k_fattn<<<dim3(1024),   256, 0, stream>>>(qws, kws, vtws, attn, outv);
    k_pe4  <<<dim3(4096),   256, 0, stream>>>(attn, pe, pesp);
    k_out  <<<dim3(256),    512, 0, stream>>>(outv, pesp, Wpe, bpe, Wproj, out);
}

// Round 23
// 113.909 us; speedup vs baseline: 1.0562x; 1.0562x over previous
//
#include <hip/hip_runtime.h>
#include <hip/hip_bf16.h>

#define DIM   128
#define NH    8
#define INNER 512
#define HD    64
#define BSZ   4
#define NSEQ  1024
#define PEC   32
#define BH    32   // BSZ*NH

typedef __attribute__((ext_vector_type(4))) float f32x4;
typedef __attribute__((ext_vector_type(2))) float f32x2;
typedef __attribute__((ext_vector_type(8))) short s16x8;
typedef __attribute__((ext_vector_type(4))) unsigned short u16x4;
typedef __attribute__((ext_vector_type(2))) unsigned int u32x2;
typedef __attribute__((ext_vector_type(4))) unsigned int u32x4;

__device__ __forceinline__ unsigned short f2bf(float f) {
    unsigned u = __float_as_uint(f);
    u += 0x7fffu + ((u >> 16) & 1u);
    return (unsigned short)(u >> 16);
}

__device__ __forceinline__ float bf2f(short s) {
    return __uint_as_float(((unsigned)(unsigned short)s) << 16);
}

__device__ __forceinline__ s16x8 load8bf(const float* p) {
    f32x4 a = *(const f32x4*)p;
    f32x4 b = *(const f32x4*)(p + 4);
    s16x8 r;
    r[0] = (short)f2bf(a[0]); r[1] = (short)f2bf(a[1]);
    r[2] = (short)f2bf(a[2]); r[3] = (short)f2bf(a[3]);
    r[4] = (short)f2bf(b[0]); r[5] = (short)f2bf(b[1]);
    r[6] = (short)f2bf(b[2]); r[7] = (short)f2bf(b[3]);
    return r;
}

__device__ __forceinline__ f32x4 mfma16(s16x8 a, s16x8 b, f32x4 c) {
    return __builtin_amdgcn_mfma_f32_16x16x32_bf16(a, b, c, 0, 0, 0);
}

// ---------------------------------------------------------------------------
// K1 v3: q/k/v projections, LDS-staged x + 4 m-subtiles per wave.  [R15]
// grid (24, 64), block 256.
// ---------------------------------------------------------------------------
__global__ __launch_bounds__(256) void k_qkv(
    const float* __restrict__ x,
    const float* __restrict__ Wq, const float* __restrict__ Wk,
    const float* __restrict__ Wv, const float* __restrict__ bv,
    unsigned short* __restrict__ qws, unsigned short* __restrict__ kws,
    unsigned short* __restrict__ vtws)
{
    __shared__ unsigned short xs[64][136];   // 17.4 KB, +8 pad
    int lane = threadIdx.x & 63, wave = threadIdx.x >> 6;
    int lr = lane & 15, lg = lane >> 4;
    int ct   = blockIdx.x * 4 + wave;        // 0..95 column tile over 1536 cols
    int col0 = ct * 16;
    int m0   = blockIdx.y * 64;

    int tid = threadIdx.x;
    #pragma unroll
    for (int it = 0; it < 4; ++it) {
        int flat = it * 256 + tid;           // 0..1023
        int r = flat >> 4, c8 = (flat & 15) * 8;
        *(s16x8*)&xs[r][c8] = load8bf(x + (m0 + r) * DIM + c8);
    }
    __syncthreads();

    const float* W; int cbase; int which = col0 >> 9;
    if (which == 0)      { W = Wq; cbase = col0; }
    else if (which == 1) { W = Wk; cbase = col0 - 512; }
    else                 { W = Wv; cbase = col0 - 1024; }

    const float* wrow = W + (cbase + lr) * DIM;
    s16x8 bfr[4];
    #pragma unroll
    for (int kt = 0; kt < 4; ++kt) bfr[kt] = load8bf(wrow + kt * 32 + lg * 8);

    if (which == 2) {
        int colW = cbase + lr;
        int h = colW >> 6, d = colW & 63;
        float bias = bv[colW];
        #pragma unroll
        for (int ms = 0; ms < 4; ++ms) {
            f32x4 acc = {0.f, 0.f, 0.f, 0.f};
            #pragma unroll
            for (int kt = 0; kt < 4; ++kt) {
                s16x8 a = *(const s16x8*)&xs[ms * 16 + lr][kt * 32 + lg * 8];
                acc = mfma16(a, bfr[kt], acc);
            }
            int mB = m0 + ms * 16 + lg * 4;
            int b  = mB >> 10;
            int bh = b * NH + h;
            u16x4 pk;
            #pragma unroll
            for (int v = 0; v < 4; ++v) pk[v] = f2bf(acc[v] + bias);
            int n0 = mB & 1023;
            *(u16x4*)(vtws + (bh * HD + d) * NSEQ + n0) = pk;
        }
    } else {
        int h = cbase >> 6;
        int dbase = (cbase & 63) + lg * 4;
        unsigned short* dst = (which == 0) ? qws : kws;
        float scale = (which == 0) ? 0.125f : 1.0f;
        #pragma unroll
        for (int ms = 0; ms < 4; ++ms) {
            f32x4 acc = {0.f, 0.f, 0.f, 0.f};
            #pragma unroll
            for (int kt = 0; kt < 4; ++kt) {
                s16x8 a = *(const s16x8*)&xs[ms * 16 + lr][kt * 32 + lg * 8];
                acc = mfma16(bfr[kt], a, acc);   // A=W rows, B=x rows
            }
            int m = m0 + ms * 16 + lr;
            int b = m >> 10, n = m & 1023;
            int bh = b * NH + h;
            u16x4 pk;
            #pragma unroll
            for (int v = 0; v < 4; ++v) pk[v] = f2bf(acc[v] * scale);
            *(u16x4*)(dst + ((size_t)bh * NSEQ + n) * HD + dbase) = pk;
        }
    }
}

// ---------------------------------------------------------------------------
// K2 v9: k_fattn — flash attention per (bh, 32-row i-tile).  [R17]
//   P copy-out as fp8 e4m3 x256; PV keeps bf16 P in LDS.
// grid 1024 (XCD-pinned bh), block 256.
// ---------------------------------------------------------------------------
__global__ __launch_bounds__(256, 2) void k_fattn(
    const unsigned short* __restrict__ qws, const unsigned short* __restrict__ kws,
    const unsigned short* __restrict__ vtws,
    unsigned char* __restrict__ attn8, float* __restrict__ outv)
{
    __shared__ unsigned short Pl[32 * 1024];   // 64 KB P [i-local][j] swizzled
    __shared__ float mlb[4][2][16][2];         // [wave][i-half][lr][{max,sum}]
    int lane = threadIdx.x & 63, wave = threadIdx.x >> 6;
    int lr = lane & 15, lg = lane >> 4;
    int L = blockIdx.x;
    int bh = (L & 7) * 4 + ((L >> 3) & 3);   // XCD-pinned: K/V L2-resident
    int i0 = (L >> 5) * 32;

    auto paddr = [&](int r, int jb) -> char* {
        unsigned mask = (unsigned)(((r & 7) << 4) | ((r & 3) << 7));
        return (char*)Pl + (unsigned)(r * 2048) + ((unsigned)jb ^ mask);
    };

    // q fragments (B operand: B-row = i)
    s16x8 qf[2][2];
    #pragma unroll
    for (int m = 0; m < 2; ++m) {
        const unsigned short* qrow = qws + (bh * NSEQ + i0 + m * 16 + lr) * HD;
        qf[m][0] = *(const s16x8*)(qrow + lg * 8);
        qf[m][1] = *(const s16x8*)(qrow + 32 + lg * 8);
    }

    // ---- phase A: S for this wave's j-quarter, in registers ----
    f32x4 s[16][2];
    #pragma unroll
    for (int jc = 0; jc < 16; ++jc) {
        const unsigned short* krow =
            kws + (bh * NSEQ + wave * 256 + jc * 16 + lr) * HD + lg * 8;
        s16x8 kf0 = *(const s16x8*)(krow);
        s16x8 kf1 = *(const s16x8*)(krow + 32);
        #pragma unroll
        for (int m = 0; m < 2; ++m) {
            f32x4 acc = {0.f, 0.f, 0.f, 0.f};
            acc = mfma16(kf0, qf[m][0], acc);
            s[jc][m] = mfma16(kf1, qf[m][1], acc);
        }
    }

    // wave-local stats per i
    float mx[2], sm[2];
    #pragma unroll
    for (int m = 0; m < 2; ++m) {
        float v = -3.0e38f;
        #pragma unroll
        for (int jc = 0; jc < 16; ++jc) {
            f32x4 t = s[jc][m];
            v = fmaxf(v, fmaxf(fmaxf(t[0], t[1]), fmaxf(t[2], t[3])));
        }
        v = fmaxf(v, __shfl_xor(v, 16));
        v = fmaxf(v, __shfl_xor(v, 32));
        mx[m] = v;
    }
    #pragma unroll
    for (int m = 0; m < 2; ++m) {
        float sum = 0.f;
        #pragma unroll
        for (int jc = 0; jc < 16; ++jc) {
            f32x4 t = s[jc][m];
            #pragma unroll
            for (int u = 0; u < 4; ++u) { t[u] = __expf(t[u] - mx[m]); sum += t[u]; }
            s[jc][m] = t;
        }
        sum += __shfl_xor(sum, 16);
        sum += __shfl_xor(sum, 32);
        sm[m] = sum;
    }
    if (lg == 0) {
        #pragma unroll
        for (int m = 0; m < 2; ++m) {
            mlb[wave][m][lr][0] = mx[m];
            mlb[wave][m][lr][1] = sm[m];
        }
    }
    __syncthreads();

    // global M, L across the 4 waves; per-wave normalization factor
    float f[2];
    #pragma unroll
    for (int m = 0; m < 2; ++m) {
        float M = -3.0e38f;
        #pragma unroll
        for (int w = 0; w < 4; ++w) M = fmaxf(M, mlb[w][m][lr][0]);
        float Ls = 0.f;
        #pragma unroll
        for (int w = 0; w < 4; ++w)
            Ls += mlb[w][m][lr][1] * __expf(mlb[w][m][lr][0] - M);
        f[m] = __expf(mx[m] - M) / Ls;
    }

    // scale + pack bf16 -> LDS P (wave-private j columns, disjoint)
    #pragma unroll
    for (int jc = 0; jc < 16; ++jc) {
        #pragma unroll
        for (int m = 0; m < 2; ++m) {
            f32x4 t = s[jc][m];
            unsigned lo = (unsigned)f2bf(t[0] * f[m]) | ((unsigned)f2bf(t[1] * f[m]) << 16);
            unsigned hi = (unsigned)f2bf(t[2] * f[m]) | ((unsigned)f2bf(t[3] * f[m]) << 16);
            u32x2 pk = {lo, hi};
            int r  = m * 16 + lr;
            int jb = (wave * 512) + (jc * 32) + (lg * 8);
            *(u32x2*)paddr(r, jb) = pk;
        }
    }
    __syncthreads();

    // ---- P copy-out FIRST as fp8 (x256): 16 j per lane, one 16B store ----
    #pragma unroll
    for (int r8 = 0; r8 < 8; ++r8) {
        int r = wave * 8 + r8;
        s16x8 a = *(s16x8*)paddr(r, lane * 32);
        s16x8 b = *(s16x8*)paddr(r, lane * 32 + 16);
        u32x4 w;
        #pragma unroll
        for (int q = 0; q < 2; ++q) {
            s16x8 v = q ? b : a;
            #pragma unroll
            for (int dw = 0; dw < 2; ++dw) {
                unsigned pk = __builtin_amdgcn_cvt_pk_fp8_f32(
                    bf2f(v[dw * 4 + 0]) * 256.f, bf2f(v[dw * 4 + 1]) * 256.f, 0u, false);
                pk = __builtin_amdgcn_cvt_pk_fp8_f32(
                    bf2f(v[dw * 4 + 2]) * 256.f, bf2f(v[dw * 4 + 3]) * 256.f, pk, true);
                w[q * 2 + dw] = pk;
            }
        }
        *(u32x4*)(attn8 + ((size_t)(i0 + r) * BH + bh) * NSEQ + lane * 16) = w;
    }

    // ---- phase B: PV; wave owns d-16 (all j from LDS, bf16) ----
    int d0 = wave * 16;
    const unsigned short* vrow = vtws + (bh * HD + d0 + lr) * NSEQ + lg * 8;
    f32x4 o0 = {0.f, 0.f, 0.f, 0.f};
    f32x4 o1 = {0.f, 0.f, 0.f, 0.f};
    #pragma unroll
    for (int kt = 0; kt < 32; ++kt) {
        s16x8 bf = *(const s16x8*)(vrow + kt * 32);
        s16x8 a0 = *(s16x8*)paddr(lr,      kt * 64 + lg * 16);
        s16x8 a1 = *(s16x8*)paddr(16 + lr, kt * 64 + lg * 16);
        o0 = mfma16(a0, bf, o0);
        o1 = mfma16(a1, bf, o1);
    }
    float* orow = outv + (bh * NSEQ + i0) * HD;
    #pragma unroll
    for (int v = 0; v < 4; ++v) {
        orow[(lg * 4 + v) * HD + d0 + lr]      = o0[v];
        orow[(16 + lg * 4 + v) * HD + d0 + lr] = o1[v];
    }
}

// ---------------------------------------------------------------------------
// K3 v8: k_peout — pe-GEMM fused with comb+proj epilogue.  [R18, best=114.0]
//   Per block (one i): pes tile = attn8[i] @ pe[i] (wave-private barrier-free
//   MFMA loop); pes kept in LDS; t rows built in LDS; out rows {b*1024+i}
//   = t @ Wproj^T via padded-M=16 MFMA.
// grid 1024, block 256 (4 waves).  LDS 36 KB -> 4 blocks/CU.
// ---------------------------------------------------------------------------
__global__ __launch_bounds__(256) void k_peout(
    const unsigned char* __restrict__ attn8, const float* __restrict__ pe,
    const float* __restrict__ outv,
    const float* __restrict__ Wpe, const float* __restrict__ bpe,
    const float* __restrict__ Wproj, float* __restrict__ out)
{
    __shared__ char smem[36 * 1024];
    typedef unsigned short ptrow_t[2][PEC][40];
    ptrow_t* pt = (ptrow_t*)smem;
    float (*part)[BH][PEC] = (float (*)[BH][PEC])(smem + 20480);

    int i = blockIdx.x;
    int tid = threadIdx.x;
    int lane = tid & 63, wave = tid >> 6;
    int lr = lane & 15, lg = lane >> 4;
    int jp = lane & 15, cg = lane >> 4;            // staging roles
    const float* pei = pe + (size_t)i * NSEQ * PEC;
    int jbase = wave * 256;

    // all 16 A-fragments upfront: fp8 -> f32 (pair decode) -> bf16
    s16x8 af[8][2];
    #pragma unroll
    for (int t = 0; t < 8; ++t) {
        #pragma unroll
        for (int mh = 0; mh < 2; ++mh) {
            const unsigned char* ap =
                attn8 + ((size_t)i * BH + mh * 16 + lr) * NSEQ + jbase + t * 32 + lg * 8;
            u32x2 dd = *(const u32x2*)ap;
            f32x2 p0 = __builtin_amdgcn_cvt_pk_f32_fp8(dd[0], false);
            f32x2 p1 = __builtin_amdgcn_cvt_pk_f32_fp8(dd[0], true);
            f32x2 p2 = __builtin_amdgcn_cvt_pk_f32_fp8(dd[1], false);
            f32x2 p3 = __builtin_amdgcn_cvt_pk_f32_fp8(dd[1], true);
            s16x8 fv;
            fv[0] = (short)f2bf(p0[0]); fv[1] = (short)f2bf(p0[1]);
            fv[2] = (short)f2bf(p1[0]); fv[3] = (short)f2bf(p1[1]);
            fv[4] = (short)f2bf(p2[0]); fv[5] = (short)f2bf(p2[1]);
            fv[6] = (short)f2bf(p3[0]); fv[7] = (short)f2bf(p3[1]);
            af[t][mh] = fv;
        }
    }

    f32x4 r0, r1, r2, r3;        // pe stage registers
    auto issue = [&](int t) {
        const float* s0 = pei + (size_t)(jbase + t * 32 + jp * 2) * PEC + cg * 8;
        r0 = *(const f32x4*)(s0);
        r1 = *(const f32x4*)(s0 + 4);
        r2 = *(const f32x4*)(s0 + PEC);
        r3 = *(const f32x4*)(s0 + PEC + 4);
    };
    auto commit = [&](int buf) {
        #pragma unroll
        for (int cc = 0; cc < 4; ++cc) {
            unsigned lo = f2bf(r0[cc]), hi = f2bf(r2[cc]);
            *(unsigned*)&pt[wave][buf][cg * 8 + cc][jp * 2] = lo | (hi << 16);
        }
        #pragma unroll
        for (int cc = 0; cc < 4; ++cc) {
            unsigned lo = f2bf(r1[cc]), hi = f2bf(r3[cc]);
            *(unsigned*)&pt[wave][buf][cg * 8 + 4 + cc][jp * 2] = lo | (hi << 16);
        }
    };

    f32x4 acc00 = {0.f,0.f,0.f,0.f}, acc01 = {0.f,0.f,0.f,0.f};
    f32x4 acc10 = {0.f,0.f,0.f,0.f}, acc11 = {0.f,0.f,0.f,0.f};

    issue(0); commit(0);
    issue(1);
    #pragma unroll
    for (int t = 0; t < 8; ++t) {
        int cur = t & 1;
        s16x8 bf0 = *(const s16x8*)&pt[wave][cur][lr][lg * 8];
        s16x8 bf1 = *(const s16x8*)&pt[wave][cur][16 + lr][lg * 8];
        acc00 = mfma16(af[t][0], bf0, acc00);
        acc01 = mfma16(af[t][0], bf1, acc01);
        acc10 = mfma16(af[t][1], bf0, acc10);
        acc11 = mfma16(af[t][1], bf1, acc11);
        if (t < 7) {
            commit(cur ^ 1);         // regs currently hold tile t+1
            if (t < 6) issue(t + 2);
        }
    }

    // partial store: C row = bh-in-half = lg*4+v, col = c-in-half = lr
    #pragma unroll
    for (int v = 0; v < 4; ++v) {
        part[wave][lg * 4 + v][lr]           = acc00[v];
        part[wave][lg * 4 + v][16 + lr]      = acc01[v];
        part[wave][16 + lg * 4 + v][lr]      = acc10[v];
        part[wave][16 + lg * 4 + v][16 + lr] = acc11[v];
    }
    __syncthreads();

    // reduce 4 wave-partials into registers (x 1/256 fp8 scale)
    int bhr = tid >> 3, c0 = (tid & 7) * 4;
    f32x4 s = *(f32x4*)&part[0][bhr][c0];
    #pragma unroll
    for (int w = 1; w < 4; ++w) {
        f32x4 q = *(f32x4*)&part[w][bhr][c0];
        s[0] += q[0]; s[1] += q[1]; s[2] += q[2]; s[3] += q[3];
    }
    const float inv256 = 1.0f / 256.0f;
    s[0] *= inv256; s[1] *= inv256; s[2] *= inv256; s[3] *= inv256;
    __syncthreads();   // all part reads done before region B is repurposed

    // ---- repurpose region B: pes_s + wpe_s + bpe_s ----
    float (*pes_s)[33] = (float (*)[33])(smem + 20480);
    float (*wpe_s)[33] = (float (*)[33])(smem + 20480 + 4224);
    float* bpe_s = (float*)(smem + 20480 + 4224 + 8448);
    #pragma unroll
    for (int v = 0; v < 4; ++v) pes_s[bhr][c0 + v] = s[v];
    for (int idx = tid; idx < HD * PEC; idx += 256)
        wpe_s[idx >> 5][idx & 31] = Wpe[idx];
    if (tid < HD) bpe_s[tid] = bpe[tid];
    __syncthreads();

    // ---- t-build: rows b=0..3 (position i), bf16 into tl (region A) ----
    unsigned short (*tl)[520] = (unsigned short (*)[520])smem;
    {
        int b  = tid >> 6;               // 0..3
        int h  = (tid >> 3) & 7;
        int d0 = (tid & 7) * 8;
        int bh = b * NH + h;
        const float* ovp = outv + ((size_t)bh * NSEQ + i) * HD + d0;
        f32x4 ov0 = *(const f32x4*)(ovp);
        f32x4 ov1 = *(const f32x4*)(ovp + 4);
        float pr[PEC];
        #pragma unroll
        for (int c = 0; c < PEC; ++c) pr[c] = pes_s[bh][c];
        s16x8 pk;
        #pragma unroll
        for (int dd = 0; dd < 8; ++dd) {
            float acc = bpe_s[d0 + dd] + (dd < 4 ? ov0[dd & 3] : ov1[dd & 3]);
            #pragma unroll
            for (int c = 0; c < PEC; ++c) acc += pr[c] * wpe_s[d0 + dd][c];
            pk[dd] = (short)f2bf(acc);
        }
        *(s16x8*)&tl[b][h * HD + d0] = pk;
    }
    __syncthreads();

    // ---- proj: out rows {b*1024+i} = t @ Wproj^T, padded-M=16 MFMA ----
    #pragma unroll
    for (int nt = 0; nt < 2; ++nt) {
        int n0 = wave * 32 + nt * 16;
        const float* brow = Wproj + (n0 + lr) * INNER;
        f32x4 acc = {0.f, 0.f, 0.f, 0.f};
        #pragma unroll
        for (int kt = 0; kt < 16; ++kt) {
            s16x8 afr = *(const s16x8*)&tl[lr][kt * 32 + lg * 8];
            s16x8 bfr = load8bf(brow + kt * 32 + lg * 8);
            acc = mfma16(afr, bfr, acc);
        }
        if (lg == 0) {
            #pragma unroll
            for (int v = 0; v < 4; ++v)
                out[((size_t)(v * NSEQ + i)) * DIM + n0 + lr] = acc[v];
        }
    }
}

// ---------------------------------------------------------------------------
// Workspace layout (52 MiB used):
//   [ 0,  4) MiB q_ws   bf16 [bh][n][64]
//   [ 4,  8) MiB k_ws   bf16 [bh][n][64]
//   [ 8, 12) MiB vT_ws  bf16 [bh][64][n]
//   [12, 44) MiB attn8  fp8  [i][bh][j]  (P x256, e4m3)
//   [44, 52) MiB outv   f32  [bh][n][64]
// FINAL: exact revert to R18 (best measured: 114.0 us; 195.6 -> 114.0 =
// 1.72x).  Campaign summary: fusion 5->3 kernels, fp8 P (halved attn
// traffic), LDS-staged qkv, fused epilogue.  Refuted: occupancy/ILP tweaks
// (R9-R11), VALU pe-fuse (R20, -138), split-K (R22, -6), allocator games
// (R19/R21, null).  Remaining gap to the ~36 us traffic floor is pe-phase
// dependent-chain latency, structural for this decomposition.
// ---------------------------------------------------------------------------
extern "C" void kernel_launch(void* const* d_in, const int* in_sizes, int n_in,
                              void* d_out, int out_size, void* d_ws, size_t ws_size,
                              hipStream_t stream)
{
    const float* x     = (const float*)d_in[0];
    const float* pe    = (const float*)d_in[1];
    const float* Wq    = (const float*)d_in[2];
    const float* Wk    = (const float*)d_in[3];
    const float* Wv    = (const float*)d_in[4];
    const float* bv    = (const float*)d_in[5];
    const float* Wproj = (const float*)d_in[6];
    const float* Wpe   = (const float*)d_in[7];
    const float* bpe   = (const float*)d_in[8];
    float* out = (float*)d_out;

    char* ws = (char*)d_ws;
    unsigned short* qws  = (unsigned short*)(ws);
    unsigned short* kws  = (unsigned short*)(ws + ( 4u << 20));
    unsigned short* vtws = (unsigned short*)(ws + ( 8u << 20));
    unsigned char*  attn = (unsigned char*) (ws + (12u << 20));
    float*          outv = (float*)         (ws + (44u << 20));

    k_qkv  <<<dim3(24, 64), 256, 0, stream>>>(x, Wq, Wk, Wv, bv, qws, kws, vtws);
    k_fattn<<<dim3(1024),   256, 0, stream>>>(qws, kws, vtws, attn, outv);
    k_peout<<<dim3(1024),   256, 0, stream>>>(attn, pe, outv, Wpe, bpe, Wproj, out);
}